// Round 20
// baseline (205.057 us; speedup 1.0000x reference)
//
#include <hip/hip_runtime.h>

typedef __bf16 bf16x8 __attribute__((ext_vector_type(8)));
typedef float  f32x4  __attribute__((ext_vector_type(4)));

#define CC 64
#define HWSZ 4096
#define CHWSZ 262144
#define NE 512
#define NPIX 131072
#define PIXBS 256             // screen tile (4 m-tiles/wave)
#define NTILE (NPIX / PIXBS)  // 512
#define FLAG_T 0.024f         // 0.012 split-err + masked quantum + slack (r16-r19-proven)
#define FB_T   0.05f          // 3-code-cluster fallback threshold
#define NSTRIPE 32

#define ET_OFF 0              // 512 codes * 256 B (hi64|lo64 bf16), XOR-swizzled rows
#define E2_OFF 131072         // 512 * 4 (exact)
#define HIST_OFF 133120       // 32 stripes * 512 * 4 = 65536
#define BATCH_OFF 198656      // 32 * 4
#define PART_OFF 198784       // 131072 pixels * 4 quarters * 8 B = 4194304
#define CNT_OFF 4393088       // 512 tile counters * 4

__device__ __forceinline__ float bf2f(unsigned short u) {
    unsigned int x = ((unsigned int)u) << 16;
    return __builtin_bit_cast(float, x);
}
__device__ __forceinline__ unsigned short f2bf(float f) {
    unsigned int x = __builtin_bit_cast(unsigned int, f);
    unsigned int r = x + 0x7fffu + ((x >> 16) & 1u);
    return (unsigned short)(r >> 16);
}
__device__ __forceinline__ float bcf(unsigned u) { return __builtin_bit_cast(float, u); }
__device__ __forceinline__ unsigned umin_(unsigned a, unsigned b) { return a < b ? a : b; }
__device__ __forceinline__ unsigned umax_(unsigned a, unsigned b) { return a > b ? a : b; }
__device__ __forceinline__ void gload16(const void* g, void* l) {
    __builtin_amdgcn_global_load_lds(
        (const __attribute__((address_space(1))) unsigned int*)g,
        (__attribute__((address_space(3))) unsigned int*)l, 16, 0, 0);
}

// ---- init (8 blocks): exact e2[512]; embed^T hi/lo bf16 PRE-SWIZZLED; zero hist/cnt ----
__global__ __launch_bounds__(512) void vq_init(const float* __restrict__ eg, char* __restrict__ ws) {
    const int tid = threadIdx.x, blk = blockIdx.x;
    if (tid < 64) {
        int n = blk * 64 + tid;
        float s = 0.f;
        #pragma unroll 8
        for (int k = 0; k < CC; ++k) { float v = eg[k * NE + n]; s = __fadd_rn(s, __fmul_rn(v, v)); }
        ((float*)(ws + E2_OFF))[n] = s;
    }
    char* et = ws + ET_OFF;
    #pragma unroll
    for (int it = 0; it < 8; ++it) {
        int idx = blk * 4096 + it * 512 + tid;   // global word index
        int n = idx >> 6, w = idx & 63;
        int k = (w & 31) << 1;
        float v0 = eg[k * NE + n], v1 = eg[(k + 1) * NE + n];
        unsigned short c0, c1;
        if (w < 32) { c0 = f2bf(v0); c1 = f2bf(v1); }
        else {
            unsigned short h0 = f2bf(v0), h1 = f2bf(v1);
            c0 = f2bf(__fsub_rn(v0, bf2f(h0)));
            c1 = f2bf(__fsub_rn(v1, bf2f(h1)));
        }
        int b = (n * 256 + w * 4) ^ ((n & 15) << 4);   // row-local XOR swizzle (matches reader)
        *(unsigned int*)(et + b) = (unsigned int)c0 | ((unsigned int)c1 << 16);
    }
    unsigned int* h32 = (unsigned int*)(ws + HIST_OFF);
    for (int i = blk * 2048 + tid; i < (blk + 1) * 2048; i += 512) h32[i] = 0u;
    if (blk == 0) {
        if (tid < NTILE) ((unsigned int*)(ws + CNT_OFF))[tid] = 0u;
        if (tid < 32) ((float*)(ws + BATCH_OFF))[tid] = 0.f;
    }
}

// ---- K1: split-bf16 screen (r19-verified math) + last-quarter FINISHER that runs the
// r16-proven combine + 8-candidate recheck + hist + apply while parts/x are L2-hot. ----
__global__ __launch_bounds__(256) void vq_screen(const float* __restrict__ xg,
                                                 const float* __restrict__ eg,
                                                 float* __restrict__ outg,
                                                 char* __restrict__ ws) {
    __shared__ __align__(16) char btb[32768];   // 128 codes x 256 B (hi|lo), swizzled
    __shared__ float e2q[128];
    // finisher-phase storage (adds ~4.4KB; total ~37.7KB -> still 4 blocks/CU)
    __shared__ float e2s[NE];
    __shared__ float xp[4][CC];
    __shared__ int idxs[PIXBS];
    __shared__ unsigned char flg[PIXBS];
    __shared__ float wsum[4];
    __shared__ int amLast;

    const int tid  = threadIdx.x;
    const int lane = tid & 63;
    const int wv   = tid >> 6;
    const int l15  = lane & 15;
    const int l4   = lane >> 4;
    const int blk  = blockIdx.x;
    const int g    = blk >> 5;
    const int tile = g * 8 + (blk & 7);
    const int q    = (blk >> 3) & 3;
    const int pix0 = tile * PIXBS;
    const int bb   = pix0 >> 12;
    const size_t xbase = (size_t)bb * CHWSZ + (pix0 & 4095);

    #pragma unroll
    for (int i = 0; i < 8; ++i)
        gload16(ws + ET_OFF + (size_t)q * 32768 + i * 4096 + tid * 16, &btb[i * 4096 + tid * 16]);
    if (tid < 128) e2q[tid] = ((const float*)(ws + E2_OFF))[q * 128 + tid] + 512.f;   // biased

    // A fragments direct from global; native bf16 casts; 4 m-tiles = 64 pixels/wave
    bf16x8 ah[4][2], al[4][2];
    #pragma unroll
    for (int mt = 0; mt < 4; ++mt) {
        const int p = (4 * wv + mt) * 16 + l15;
        #pragma unroll
        for (int kh = 0; kh < 2; ++kh) {
            float v[8];
            #pragma unroll
            for (int e = 0; e < 8; ++e)
                v[e] = xg[xbase + (size_t)(kh * 32 + l4 * 8 + e) * HWSZ + p];
            bf16x8 hv, lv;
            #pragma unroll
            for (int e = 0; e < 8; ++e) {
                __bf16 hb = (__bf16)v[e];
                hv[e] = hb;
                lv[e] = (__bf16)__fsub_rn(v[e], (float)hb);
            }
            ah[mt][kh] = hv;
            al[mt][kh] = lv;
        }
    }
    asm volatile("s_waitcnt vmcnt(0) lgkmcnt(0)" ::: "memory");
    __builtin_amdgcn_sched_barrier(0);
    __builtin_amdgcn_s_barrier();          // btb + e2q resident
    __builtin_amdgcn_sched_barrier(0);

    unsigned k1[4][4], k2[4][4];
    #pragma unroll
    for (int mt = 0; mt < 4; ++mt)
        #pragma unroll
        for (int r = 0; r < 4; ++r) { k1[mt][r] = 0xFFFFFFFFu; k2[mt][r] = 0xFFFFFFFFu; }

    #pragma unroll
    for (int gg = 0; gg < 8; ++gg) {
        const int r = gg * 16 + l15;          // quarter-local code 0..127
        const int ro = r * 256 + l4 * 16;
        const int sw2 = (r & 15) << 4;
        bf16x8 bh0 = *(const bf16x8*)(btb + ((ro +   0) ^ sw2));
        bf16x8 bh1 = *(const bf16x8*)(btb + ((ro +  64) ^ sw2));
        bf16x8 bl0 = *(const bf16x8*)(btb + ((ro + 128) ^ sw2));
        bf16x8 bl1 = *(const bf16x8*)(btb + ((ro + 192) ^ sw2));
        float e2v = e2q[r];
        #pragma unroll
        for (int mt = 0; mt < 4; ++mt) {
            f32x4 acc = (f32x4){0.f, 0.f, 0.f, 0.f};
            acc = __builtin_amdgcn_mfma_f32_16x16x32_bf16(ah[mt][0], bh0, acc, 0, 0, 0);
            acc = __builtin_amdgcn_mfma_f32_16x16x32_bf16(ah[mt][1], bh1, acc, 0, 0, 0);
            acc = __builtin_amdgcn_mfma_f32_16x16x32_bf16(ah[mt][0], bl0, acc, 0, 0, 0);
            acc = __builtin_amdgcn_mfma_f32_16x16x32_bf16(ah[mt][1], bl1, acc, 0, 0, 0);
            acc = __builtin_amdgcn_mfma_f32_16x16x32_bf16(al[mt][0], bh0, acc, 0, 0, 0);
            acc = __builtin_amdgcn_mfma_f32_16x16x32_bf16(al[mt][1], bh1, acc, 0, 0, 0);
            #pragma unroll
            for (int r2 = 0; r2 < 4; ++r2) {
                float d = __fmaf_rn(-2.f, acc[r2], e2v);       // biased +512, > 0
                unsigned u = (__builtin_bit_cast(unsigned, d) & 0xFFFFFF80u) | (unsigned)r;
                k2[mt][r2] = umin_(k2[mt][r2], umax_(u, k1[mt][r2]));
                k1[mt][r2] = umin_(k1[mt][r2], u);
            }
        }
    }

    #pragma unroll
    for (int m = 1; m < 16; m <<= 1) {
        #pragma unroll
        for (int mt = 0; mt < 4; ++mt)
            #pragma unroll
            for (int r = 0; r < 4; ++r) {
                unsigned o1 = __shfl_xor(k1[mt][r], m, 64);
                unsigned o2 = __shfl_xor(k2[mt][r], m, 64);
                k2[mt][r] = umin_(umin_(k2[mt][r], o2), umax_(k1[mt][r], o1));
                k1[mt][r] = umin_(k1[mt][r], o1);
            }
    }

    if (l15 == 0) {
        uint2* part = (uint2*)(ws + PART_OFF);
        #pragma unroll
        for (int mt = 0; mt < 4; ++mt)
            #pragma unroll
            for (int r = 0; r < 4; ++r) {
                int p = wv * 64 + mt * 16 + l4 * 4 + r;
                part[(size_t)(pix0 + p) * 4 + q] = (uint2){k1[mt][r], k2[mt][r]};
            }
    }
    __syncthreads();   // drains part stores (vmcnt) for all waves

    // ---- last-quarter handoff (no spin; G16-safe: any arrival order works) ----
    if (tid == 0) {
        __threadfence();                       // release parts device-wide
        unsigned old = atomicAdd((unsigned int*)(ws + CNT_OFF) + tile, 1u);
        amLast = (old == 3u);
    }
    __syncthreads();
    if (!amLast) return;
    __threadfence();                           // acquire other quarters' parts

    // ================= FINISHER: combine + recheck + hist + apply =================
    {
        const float* e2g = (const float*)(ws + E2_OFF);
        for (int t = tid; t < NE; t += 256) e2s[t] = e2g[t];
    }

    // combine 4 quarters; classify: 0 = safe, 1 = candidate recheck, 2 = full fallback
    {
        const uint2* part = (const uint2*)(ws + PART_OFF) + (size_t)(pix0 + tid) * 4;
        uint2 pq[4];
        #pragma unroll
        for (int qq = 0; qq < 4; ++qq) pq[qq] = part[qq];
        unsigned K1 = 0xFFFFFFFFu, K2 = 0xFFFFFFFFu;
        int gq = 0;
        #pragma unroll
        for (int qq = 0; qq < 4; ++qq) {
            K2 = umin_(umin_(K2, pq[qq].y), umax_(K1, pq[qq].x));
            if (pq[qq].x < K1) { K1 = pq[qq].x; gq = qq; }
        }
        float M1 = bcf(K1 & 0xFFFFFF80u);
        float M2 = bcf(K2 & 0xFFFFFF80u);
        int fb = 0;
        #pragma unroll
        for (int qq = 0; qq < 4; ++qq) {
            float m1q = bcf(pq[qq].x & 0xFFFFFF80u);
            float m2q = bcf(pq[qq].y & 0xFFFFFF80u);
            if (m1q - M1 < FB_T && m2q - m1q < FB_T) fb = 1;   // 3-code cluster risk
        }
        idxs[tid] = gq * 128 + (int)(K1 & 127u);
        flg[tid] = (M2 - M1 < FLAG_T) ? (fb ? 2 : 1) : 0;
    }
    __syncthreads();

    // per-wave recheck: wave wv owns pixels [64wv, 64wv+64)
    {
        bool f = flg[wv * 64 + lane] != 0;
        unsigned long long mask = __ballot(f);
        while (mask) {
            int l0 = __ffsll((long long)mask) - 1;
            mask &= mask - 1;
            int p = wv * 64 + l0;
            int mode = flg[p];
            xp[wv][lane] = xg[xbase + (size_t)lane * HWSZ + p];   // k = lane
            float rr[8];
            #pragma unroll
            for (int u = 0; u < 8; ++u) { float v = xp[wv][u]; rr[u] = __fmul_rn(v, v); }
            #pragma unroll
            for (int t2 = 1; t2 < 8; ++t2)
                #pragma unroll
                for (int u = 0; u < 8; ++u) { float v = xp[wv][t2 * 8 + u]; rr[u] = __fadd_rn(rr[u], __fmul_rn(v, v)); }
            float f2 = __fadd_rn(__fadd_rn(__fadd_rn(rr[0], rr[1]), __fadd_rn(rr[2], rr[3])),
                                 __fadd_rn(__fadd_rn(rr[4], rr[5]), __fadd_rn(rr[6], rr[7])));
            if (mode == 1) {
                // 8 candidates: quarter {min1, min2}; lane j<8 evaluates candidate j with
                // the bit-identical sequential-k fp32 chain.
                float d = 3.4e38f; int c = 0x7FFFFFFF;
                if (lane < 8) {
                    const uint2* part = (const uint2*)(ws + PART_OFF) + (size_t)(pix0 + p) * 4;
                    uint2 pq = part[lane >> 1];
                    unsigned key = (lane & 1) ? pq.y : pq.x;
                    c = (lane >> 1) * 128 + (int)(key & 127u);
                    float dot = 0.f;
                    #pragma unroll 8
                    for (int k = 0; k < CC; ++k) dot = __fmaf_rn(xp[wv][k], eg[k * NE + c], dot);
                    d = __fadd_rn(__fmaf_rn(-2.f, dot, f2), e2s[c]);
                }
                #pragma unroll
                for (int m = 1; m < 8; m <<= 1) {
                    float ov = __shfl_xor(d, m, 64);
                    int   oi = __shfl_xor(c, m, 64);
                    if (ov < d || (ov == d && oi < c)) { d = ov; c = oi; }
                }
                int nb = __shfl(c, 0, 64);
                if (lane == 0) idxs[p] = nb;
            } else {
                // full 512-code fallback (rare) — bit-identical fp32 arithmetic
                const int c0 = lane * 8;
                float dot[8];
                #pragma unroll
                for (int j = 0; j < 8; ++j) dot[j] = 0.f;
                #pragma unroll 4
                for (int k = 0; k < CC; ++k) {
                    float xv = xp[wv][k];
                    float4 aa = *(const float4*)(eg + k * NE + c0);
                    float4 bbv = *(const float4*)(eg + k * NE + c0 + 4);
                    dot[0] = __fmaf_rn(xv, aa.x, dot[0]); dot[1] = __fmaf_rn(xv, aa.y, dot[1]);
                    dot[2] = __fmaf_rn(xv, aa.z, dot[2]); dot[3] = __fmaf_rn(xv, aa.w, dot[3]);
                    dot[4] = __fmaf_rn(xv, bbv.x, dot[4]); dot[5] = __fmaf_rn(xv, bbv.y, dot[5]);
                    dot[6] = __fmaf_rn(xv, bbv.z, dot[6]); dot[7] = __fmaf_rn(xv, bbv.w, dot[7]);
                }
                float best = 3.4e38f; int bidx = 0;
                #pragma unroll
                for (int j = 0; j < 8; ++j) {
                    float d = __fadd_rn(__fmaf_rn(-2.f, dot[j], f2), e2s[c0 + j]);
                    if (d < best) { best = d; bidx = c0 + j; }
                }
                #pragma unroll
                for (int m = 1; m < 64; m <<= 1) {
                    float ov = __shfl_xor(best, m, 64);
                    int   oi = __shfl_xor(bidx, m, 64);
                    if (ov < best || (ov == best && oi < bidx)) { best = ov; bidx = oi; }
                }
                if (lane == 0) idxs[p] = bidx;
            }
        }
    }
    __syncthreads();

    atomicAdd((unsigned int*)(ws + HIST_OFF) + (blk & (NSTRIPE - 1)) * NE + idxs[tid], 1u);

    // apply: float4 x re-read (L2-hot); exact ref arithmetic out = x + (q - x); sq loss
    float sq = 0.f;
    for (int t = tid; t < 4096; t += 256) {
        int cc = t >> 6, p4 = (t & 63) << 2;
        float4 vr = *(const float4*)(xg + xbase + (size_t)cc * HWSZ + p4);
        float vv[4] = {vr.x, vr.y, vr.z, vr.w};
        float4 ov;
        float* ovp = &ov.x;
        #pragma unroll
        for (int j = 0; j < 4; ++j) {
            float qv = eg[cc * NE + idxs[p4 + j]];
            float d = __fsub_rn(qv, vv[j]);
            ovp[j] = __fadd_rn(vv[j], d);
            sq = __fmaf_rn(d, d, sq);
        }
        *(float4*)(outg + xbase + (size_t)cc * HWSZ + p4) = ov;
    }
    #pragma unroll
    for (int m = 32; m >= 1; m >>= 1) sq += __shfl_down(sq, m, 64);
    if (lane == 0) wsum[wv] = sq;
    __syncthreads();
    if (tid == 0)
        atomicAdd((float*)(ws + BATCH_OFF) + bb, wsum[0] + wsum[1] + wsum[2] + wsum[3]);
}

// ---- finalize: sum hist stripes, diff[32], perplexity ----
__global__ __launch_bounds__(512) void vq_fin(const char* __restrict__ ws, float* __restrict__ outg) {
    __shared__ float acc8[8];
    const int tid = threadIdx.x, lane = tid & 63, wv = tid >> 6;
    const unsigned int* h32 = (const unsigned int*)(ws + HIST_OFF);
    unsigned int h = 0;
    #pragma unroll
    for (int s = 0; s < NSTRIPE; ++s) h += h32[s * NE + tid];
    float p = (float)h * (1.f / (float)NPIX);
    float t = p * logf(p + 1e-10f);
    #pragma unroll
    for (int m = 32; m >= 1; m >>= 1) t += __shfl_down(t, m, 64);
    if (lane == 0) acc8[wv] = t;
    __syncthreads();
    if (tid < 32) outg[8388608 + tid] = ((const float*)(ws + BATCH_OFF))[tid] * (1.f / 262144.f);
    if (tid == 0) {
        float s = 0.f;
        #pragma unroll
        for (int u = 0; u < 8; ++u) s += acc8[u];
        outg[8388640] = expf(-s);
    }
}

extern "C" void kernel_launch(void* const* d_in, const int* in_sizes, int n_in,
                              void* d_out, int out_size, void* d_ws, size_t ws_size,
                              hipStream_t stream) {
    const float* xg = (const float*)d_in[0];
    const float* eg = (const float*)d_in[1];
    float* outg = (float*)d_out;
    char* ws = (char*)d_ws;
    vq_init<<<8, 512, 0, stream>>>(eg, ws);
    vq_screen<<<(NPIX / PIXBS) * 4, 256, 0, stream>>>(xg, eg, outg, ws);
    vq_fin<<<1, 512, 0, stream>>>(ws, outg);
}

// Round 21
// 76.776 us; speedup vs baseline: 2.6708x; 2.6708x over previous
//
#include <hip/hip_runtime.h>

typedef __bf16 bf16x8 __attribute__((ext_vector_type(8)));
typedef float  f32x4  __attribute__((ext_vector_type(4)));

#define CC 64
#define HWSZ 4096
#define CHWSZ 262144
#define NE 512
#define NPIX 131072
#define PIXB 128
#define FLAG_T 0.024f         // 0.012 split-err + mask quantum + slack (r16-proven)
#define FB_T   0.05f          // 3-code-cluster fallback threshold
#define NSTRIPE 32

#define ET_OFF 0              // 512 codes * 256 B (hi64|lo64 bf16), XOR-swizzled rows
#define E2_OFF 131072         // 512 * 4
#define HIST_OFF 133120       // 32 stripes * 512 * 4 = 65536
#define BATCH_OFF 198656      // 32 * 4
#define PART_OFF 198784       // 131072 pixels * 4 quarters * 8 B = 4194304
#define ETF_OFF 4393088       // transposed fp32 codebook [512][64] = 131072 B

__device__ __forceinline__ float bf2f(unsigned short u) {
    unsigned int x = ((unsigned int)u) << 16;
    return __builtin_bit_cast(float, x);
}
__device__ __forceinline__ unsigned short f2bf(float f) {
    unsigned int x = __builtin_bit_cast(unsigned int, f);
    unsigned int r = x + 0x7fffu + ((x >> 16) & 1u);
    return (unsigned short)(r >> 16);
}
__device__ __forceinline__ float bcf(unsigned u) { return __builtin_bit_cast(float, u); }
__device__ __forceinline__ unsigned umin_(unsigned a, unsigned b) { return a < b ? a : b; }
__device__ __forceinline__ unsigned umax_(unsigned a, unsigned b) { return a > b ? a : b; }
__device__ __forceinline__ void gload16(const void* g, void* l) {
    __builtin_amdgcn_global_load_lds(
        (const __attribute__((address_space(1))) unsigned int*)g,
        (__attribute__((address_space(3))) unsigned int*)l, 16, 0, 0);
}

// ---- init (8 blocks): exact e2[512]; embed^T hi/lo bf16 PRE-SWIZZLED; transposed fp32
// codebook etf[512][64] (bit-identical copies); zero hist/batch ----
__global__ __launch_bounds__(512) void vq_init(const float* __restrict__ eg, char* __restrict__ ws) {
    const int tid = threadIdx.x, blk = blockIdx.x;
    if (tid < 64) {
        int n = blk * 64 + tid;
        float s = 0.f;
        #pragma unroll 8
        for (int k = 0; k < CC; ++k) { float v = eg[k * NE + n]; s = __fadd_rn(s, __fmul_rn(v, v)); }
        ((float*)(ws + E2_OFF))[n] = s;
    }
    char* et = ws + ET_OFF;
    #pragma unroll
    for (int it = 0; it < 8; ++it) {
        int idx = blk * 4096 + it * 512 + tid;   // global word index
        int n = idx >> 6, w = idx & 63;
        int k = (w & 31) << 1;
        float v0 = eg[k * NE + n], v1 = eg[(k + 1) * NE + n];
        unsigned short c0, c1;
        if (w < 32) { c0 = f2bf(v0); c1 = f2bf(v1); }
        else {
            unsigned short h0 = f2bf(v0), h1 = f2bf(v1);
            c0 = f2bf(__fsub_rn(v0, bf2f(h0)));
            c1 = f2bf(__fsub_rn(v1, bf2f(h1)));
        }
        int b = (n * 256 + w * 4) ^ ((n & 15) << 4);   // row-local XOR swizzle (matches reader)
        *(unsigned int*)(et + b) = (unsigned int)c0 | ((unsigned int)c1 << 16);
    }
    // transposed fp32 codebook: etf[n][k] = eg[k][n] (coalesced reads over n)
    {
        float* etf = (float*)(ws + ETF_OFF);
        const int nl = tid & 63, w8 = tid >> 6;       // n_local, k-octet
        #pragma unroll
        for (int it = 0; it < 8; ++it) {
            int k = w8 * 8 + it;
            int n = blk * 64 + nl;
            etf[n * 64 + k] = eg[k * NE + n];
        }
    }
    unsigned int* h32 = (unsigned int*)(ws + HIST_OFF);
    for (int i = blk * 2048 + tid; i < (blk + 1) * 2048; i += 512) h32[i] = 0u;
    if (blk == 0 && tid < 32) ((float*)(ws + BATCH_OFF))[tid] = 0.f;
}

// ---- K1: split-bf16 screen (r16-verified, byte-identical): A direct global->reg,
// B quarter in LDS, packed-key (7-bit code) argmin, XCD-coherent quarter mapping. ----
__global__ __launch_bounds__(256) void vq_screen(const float* __restrict__ xg,
                                                 char* __restrict__ ws) {
    __shared__ __align__(16) char btb[32768];   // 128 codes x 256 B (hi|lo), swizzled
    __shared__ float e2q[128];

    const int tid  = threadIdx.x;
    const int lane = tid & 63;
    const int wv   = tid >> 6;
    const int l15  = lane & 15;
    const int l4   = lane >> 4;
    const int blk  = blockIdx.x;
    const int q    = blk >> 10;          // quarter (generation)
    const int tile = blk & 1023;         // pixel tile
    const int pix0 = tile * PIXB;
    const int bb   = pix0 >> 12;
    const size_t xbase = (size_t)bb * CHWSZ + (pix0 & 4095);

    #pragma unroll
    for (int i = 0; i < 8; ++i)
        gload16(ws + ET_OFF + (size_t)q * 32768 + i * 4096 + tid * 16, &btb[i * 4096 + tid * 16]);
    if (tid < 128) e2q[tid] = ((const float*)(ws + E2_OFF))[q * 128 + tid] + 512.f;   // biased

    bf16x8 ah[2][2], al[2][2];
    #pragma unroll
    for (int mt = 0; mt < 2; ++mt) {
        const int p = (2 * wv + mt) * 16 + l15;
        #pragma unroll
        for (int kh = 0; kh < 2; ++kh) {
            float v[8];
            #pragma unroll
            for (int e = 0; e < 8; ++e)
                v[e] = xg[xbase + (size_t)(kh * 32 + l4 * 8 + e) * HWSZ + p];
            bf16x8 hv, lv;
            #pragma unroll
            for (int e = 0; e < 8; ++e) {
                __bf16 hb = (__bf16)v[e];
                hv[e] = hb;
                lv[e] = (__bf16)__fsub_rn(v[e], (float)hb);
            }
            ah[mt][kh] = hv;
            al[mt][kh] = lv;
        }
    }
    asm volatile("s_waitcnt vmcnt(0) lgkmcnt(0)" ::: "memory");
    __builtin_amdgcn_sched_barrier(0);
    __builtin_amdgcn_s_barrier();          // the ONLY barrier: btb + e2q resident
    __builtin_amdgcn_sched_barrier(0);

    unsigned k1[2][4], k2[2][4];
    #pragma unroll
    for (int mt = 0; mt < 2; ++mt)
        #pragma unroll
        for (int r = 0; r < 4; ++r) { k1[mt][r] = 0xFFFFFFFFu; k2[mt][r] = 0xFFFFFFFFu; }

    #pragma unroll
    for (int gg = 0; gg < 8; ++gg) {
        const int r = gg * 16 + l15;          // quarter-local code 0..127
        const int ro = r * 256 + l4 * 16;
        const int sw2 = (r & 15) << 4;
        bf16x8 bh0 = *(const bf16x8*)(btb + ((ro +   0) ^ sw2));
        bf16x8 bh1 = *(const bf16x8*)(btb + ((ro +  64) ^ sw2));
        bf16x8 bl0 = *(const bf16x8*)(btb + ((ro + 128) ^ sw2));
        bf16x8 bl1 = *(const bf16x8*)(btb + ((ro + 192) ^ sw2));
        float e2v = e2q[r];
        #pragma unroll
        for (int mt = 0; mt < 2; ++mt) {
            f32x4 acc = (f32x4){0.f, 0.f, 0.f, 0.f};
            acc = __builtin_amdgcn_mfma_f32_16x16x32_bf16(ah[mt][0], bh0, acc, 0, 0, 0);
            acc = __builtin_amdgcn_mfma_f32_16x16x32_bf16(ah[mt][1], bh1, acc, 0, 0, 0);
            acc = __builtin_amdgcn_mfma_f32_16x16x32_bf16(ah[mt][0], bl0, acc, 0, 0, 0);
            acc = __builtin_amdgcn_mfma_f32_16x16x32_bf16(ah[mt][1], bl1, acc, 0, 0, 0);
            acc = __builtin_amdgcn_mfma_f32_16x16x32_bf16(al[mt][0], bh0, acc, 0, 0, 0);
            acc = __builtin_amdgcn_mfma_f32_16x16x32_bf16(al[mt][1], bh1, acc, 0, 0, 0);
            #pragma unroll
            for (int r2 = 0; r2 < 4; ++r2) {
                float d = __fmaf_rn(-2.f, acc[r2], e2v);       // biased +512, > 0
                unsigned u = (__builtin_bit_cast(unsigned, d) & 0xFFFFFF80u) | (unsigned)r;
                k2[mt][r2] = umin_(k2[mt][r2], umax_(u, k1[mt][r2]));
                k1[mt][r2] = umin_(k1[mt][r2], u);
            }
        }
    }

    #pragma unroll
    for (int m = 1; m < 16; m <<= 1) {
        #pragma unroll
        for (int mt = 0; mt < 2; ++mt)
            #pragma unroll
            for (int r = 0; r < 4; ++r) {
                unsigned o1 = __shfl_xor(k1[mt][r], m, 64);
                unsigned o2 = __shfl_xor(k2[mt][r], m, 64);
                k2[mt][r] = umin_(umin_(k2[mt][r], o2), umax_(k1[mt][r], o1));
                k1[mt][r] = umin_(k1[mt][r], o1);
            }
    }

    if (l15 == 0) {
        uint2* part = (uint2*)(ws + PART_OFF);
        #pragma unroll
        for (int mt = 0; mt < 2; ++mt)
            #pragma unroll
            for (int r = 0; r < 4; ++r) {
                int p = wv * 32 + mt * 16 + l4 * 4 + r;
                part[(size_t)(pix0 + p) * 4 + q] = (uint2){k1[mt][r], k2[mt][r]};
            }
    }
}

// ---- K2: fused combine + 8-candidate recheck (full-512 fallback) + hist + apply + sq.
// r16-proven structure; gathers + candidate dots now use the L1-resident transposed
// fp32 codebook etf (bit-identical values, same op order). ----
__global__ __launch_bounds__(256) void vq_apply(const float* __restrict__ xg,
                                                const float* __restrict__ eg,
                                                float* __restrict__ outg,
                                                char* __restrict__ ws) {
    __shared__ int idxs[PIXB];
    __shared__ unsigned char flg[PIXB];
    __shared__ float e2s[NE];
    __shared__ float xp[4][CC];
    __shared__ float wsum[4];

    const int tid  = threadIdx.x;
    const int lane = tid & 63;
    const int wv   = tid >> 6;
    const int pix0 = blockIdx.x * PIXB;
    const int bb   = pix0 >> 12;
    const size_t xbase = (size_t)bb * CHWSZ + (pix0 & 4095);
    const float* etf = (const float*)(ws + ETF_OFF);

    {
        const float* e2g = (const float*)(ws + E2_OFF);
        for (int t = tid; t < NE; t += 256) e2s[t] = e2g[t];
    }

    // combine 4 quarters; classify: 0 = safe, 1 = candidate recheck, 2 = full fallback
    if (tid < PIXB) {
        const uint2* part = (const uint2*)(ws + PART_OFF) + (size_t)(pix0 + tid) * 4;
        uint2 pq[4];
        #pragma unroll
        for (int q = 0; q < 4; ++q) pq[q] = part[q];
        unsigned K1 = 0xFFFFFFFFu, K2 = 0xFFFFFFFFu;
        int gq = 0;
        #pragma unroll
        for (int q = 0; q < 4; ++q) {
            K2 = umin_(umin_(K2, pq[q].y), umax_(K1, pq[q].x));
            if (pq[q].x < K1) { K1 = pq[q].x; gq = q; }
        }
        float M1 = bcf(K1 & 0xFFFFFF80u);
        float M2 = bcf(K2 & 0xFFFFFF80u);
        int fb = 0;
        #pragma unroll
        for (int q = 0; q < 4; ++q) {
            float m1q = bcf(pq[q].x & 0xFFFFFF80u);
            float m2q = bcf(pq[q].y & 0xFFFFFF80u);
            if (m1q - M1 < FB_T && m2q - m1q < FB_T) fb = 1;   // 3-code cluster risk
        }
        idxs[tid] = gq * 128 + (int)(K1 & 127u);
        flg[tid] = (M2 - M1 < FLAG_T) ? (fb ? 2 : 1) : 0;
    }
    __syncthreads();

    // per-wave recheck: wave wv owns pixels [32wv, 32wv+32)
    {
        bool f = (lane < 32) ? (flg[wv * 32 + lane] != 0) : false;
        unsigned long long mask = __ballot(f);
        while (mask) {
            int l0 = __ffsll((long long)mask) - 1;
            mask &= mask - 1;
            int p = wv * 32 + l0;
            int mode = flg[p];
            xp[wv][lane] = xg[xbase + (size_t)lane * HWSZ + p];   // k = lane
            float rr[8];
            #pragma unroll
            for (int u = 0; u < 8; ++u) { float v = xp[wv][u]; rr[u] = __fmul_rn(v, v); }
            #pragma unroll
            for (int t2 = 1; t2 < 8; ++t2)
                #pragma unroll
                for (int u = 0; u < 8; ++u) { float v = xp[wv][t2 * 8 + u]; rr[u] = __fadd_rn(rr[u], __fmul_rn(v, v)); }
            float f2 = __fadd_rn(__fadd_rn(__fadd_rn(rr[0], rr[1]), __fadd_rn(rr[2], rr[3])),
                                 __fadd_rn(__fadd_rn(rr[4], rr[5]), __fadd_rn(rr[6], rr[7])));
            if (mode == 1) {
                // 8 candidates: quarter {min1, min2}; lane j<8 evaluates candidate j with
                // the bit-identical sequential-k fp32 chain (etf row is contiguous).
                float d = 3.4e38f; int c = 0x7FFFFFFF;
                if (lane < 8) {
                    const uint2* part = (const uint2*)(ws + PART_OFF) + (size_t)(pix0 + p) * 4;
                    uint2 pq = part[lane >> 1];
                    unsigned key = (lane & 1) ? pq.y : pq.x;
                    c = (lane >> 1) * 128 + (int)(key & 127u);
                    const float* erow = etf + c * 64;
                    float dot = 0.f;
                    #pragma unroll 8
                    for (int k = 0; k < CC; ++k) dot = __fmaf_rn(xp[wv][k], erow[k], dot);
                    d = __fadd_rn(__fmaf_rn(-2.f, dot, f2), e2s[c]);
                }
                #pragma unroll
                for (int m = 1; m < 8; m <<= 1) {
                    float ov = __shfl_xor(d, m, 64);
                    int   oi = __shfl_xor(c, m, 64);
                    if (ov < d || (ov == d && oi < c)) { d = ov; c = oi; }
                }
                int nb = __shfl(c, 0, 64);
                if (lane == 0) idxs[p] = nb;
            } else {
                // full 512-code fallback (rare) — bit-identical fp32 arithmetic
                const int c0 = lane * 8;
                float dot[8];
                #pragma unroll
                for (int j = 0; j < 8; ++j) dot[j] = 0.f;
                #pragma unroll 4
                for (int k = 0; k < CC; ++k) {
                    float xv = xp[wv][k];
                    float4 aa = *(const float4*)(eg + k * NE + c0);
                    float4 bbv = *(const float4*)(eg + k * NE + c0 + 4);
                    dot[0] = __fmaf_rn(xv, aa.x, dot[0]); dot[1] = __fmaf_rn(xv, aa.y, dot[1]);
                    dot[2] = __fmaf_rn(xv, aa.z, dot[2]); dot[3] = __fmaf_rn(xv, aa.w, dot[3]);
                    dot[4] = __fmaf_rn(xv, bbv.x, dot[4]); dot[5] = __fmaf_rn(xv, bbv.y, dot[5]);
                    dot[6] = __fmaf_rn(xv, bbv.z, dot[6]); dot[7] = __fmaf_rn(xv, bbv.w, dot[7]);
                }
                float best = 3.4e38f; int bidx = 0;
                #pragma unroll
                for (int j = 0; j < 8; ++j) {
                    float d = __fadd_rn(__fmaf_rn(-2.f, dot[j], f2), e2s[c0 + j]);
                    if (d < best) { best = d; bidx = c0 + j; }
                }
                #pragma unroll
                for (int m = 1; m < 64; m <<= 1) {
                    float ov = __shfl_xor(best, m, 64);
                    int   oi = __shfl_xor(bidx, m, 64);
                    if (ov < best || (ov == best && oi < bidx)) { best = ov; bidx = oi; }
                }
                if (lane == 0) idxs[p] = bidx;
            }
        }
    }
    __syncthreads();

    if (tid < PIXB)
        atomicAdd((unsigned int*)(ws + HIST_OFF) + (blockIdx.x & (NSTRIPE - 1)) * NE + idxs[tid], 1u);

    // apply: float4 x re-read; gathers from L1-resident etf; exact ref arithmetic
    float sq = 0.f;
    for (int t = tid; t < 2048; t += 256) {
        int cc = t >> 5, p4 = (t & 31) << 2;
        float4 vr = *(const float4*)(xg + xbase + (size_t)cc * HWSZ + p4);
        float vv[4] = {vr.x, vr.y, vr.z, vr.w};
        float4 ov;
        float* ovp = &ov.x;
        #pragma unroll
        for (int j = 0; j < 4; ++j) {
            float qv = etf[idxs[p4 + j] * 64 + cc];
            float d = __fsub_rn(qv, vv[j]);
            ovp[j] = __fadd_rn(vv[j], d);
            sq = __fmaf_rn(d, d, sq);
        }
        *(float4*)(outg + xbase + (size_t)cc * HWSZ + p4) = ov;
    }
    #pragma unroll
    for (int m = 32; m >= 1; m >>= 1) sq += __shfl_down(sq, m, 64);
    if (lane == 0) wsum[wv] = sq;
    __syncthreads();
    if (tid == 0) atomicAdd((float*)(ws + BATCH_OFF) + bb, wsum[0] + wsum[1] + wsum[2] + wsum[3]);
}

// ---- finalize: sum hist stripes, diff[32], perplexity ----
__global__ __launch_bounds__(512) void vq_fin(const char* __restrict__ ws, float* __restrict__ outg) {
    __shared__ float acc8[8];
    const int tid = threadIdx.x, lane = tid & 63, wv = tid >> 6;
    const unsigned int* h32 = (const unsigned int*)(ws + HIST_OFF);
    unsigned int h = 0;
    #pragma unroll
    for (int s = 0; s < NSTRIPE; ++s) h += h32[s * NE + tid];
    float p = (float)h * (1.f / (float)NPIX);
    float t = p * logf(p + 1e-10f);
    #pragma unroll
    for (int m = 32; m >= 1; m >>= 1) t += __shfl_down(t, m, 64);
    if (lane == 0) acc8[wv] = t;
    __syncthreads();
    if (tid < 32) outg[8388608 + tid] = ((const float*)(ws + BATCH_OFF))[tid] * (1.f / 262144.f);
    if (tid == 0) {
        float s = 0.f;
        #pragma unroll
        for (int u = 0; u < 8; ++u) s += acc8[u];
        outg[8388640] = expf(-s);
    }
}

extern "C" void kernel_launch(void* const* d_in, const int* in_sizes, int n_in,
                              void* d_out, int out_size, void* d_ws, size_t ws_size,
                              hipStream_t stream) {
    const float* xg = (const float*)d_in[0];
    const float* eg = (const float*)d_in[1];
    float* outg = (float*)d_out;
    char* ws = (char*)d_ws;
    vq_init<<<8, 512, 0, stream>>>(eg, ws);
    vq_screen<<<(NPIX / PIXB) * 4, 256, 0, stream>>>(xg, ws);
    vq_apply<<<NPIX / PIXB, 256, 0, stream>>>(xg, eg, outg, ws);
    vq_fin<<<1, 512, 0, stream>>>(ws, outg);
}

// Round 22
// 70.422 us; speedup vs baseline: 2.9118x; 1.0902x over previous
//
#include <hip/hip_runtime.h>

typedef __bf16 bf16x8 __attribute__((ext_vector_type(8)));
typedef float  f32x4  __attribute__((ext_vector_type(4)));

#define CC 64
#define HWSZ 4096
#define CHWSZ 262144
#define NE 512
#define NPIX 131072
#define PIXB 128
#define FLAG_T 0.024f         // 0.012 split-err + mask quantum + slack (r16-proven)
#define FB_T   0.05f          // 3-code-cluster fallback threshold
#define NSTRIPE 32

#define ET_OFF 0              // 512 codes * 256 B (hi64|lo64 bf16), XOR-swizzled rows
#define E2_OFF 131072         // 512 * 4
#define HIST_OFF 133120       // 32 stripes * 512 * 4 = 65536
#define BATCH_OFF 198656      // 32 * 4
#define PART_OFF 198784       // 131072 pixels * 4 quarters * 8 B = 4194304

__device__ __forceinline__ float bf2f(unsigned short u) {
    unsigned int x = ((unsigned int)u) << 16;
    return __builtin_bit_cast(float, x);
}
__device__ __forceinline__ unsigned short f2bf(float f) {
    unsigned int x = __builtin_bit_cast(unsigned int, f);
    unsigned int r = x + 0x7fffu + ((x >> 16) & 1u);
    return (unsigned short)(r >> 16);
}
__device__ __forceinline__ float bcf(unsigned u) { return __builtin_bit_cast(float, u); }
__device__ __forceinline__ unsigned umin_(unsigned a, unsigned b) { return a < b ? a : b; }
__device__ __forceinline__ unsigned umax_(unsigned a, unsigned b) { return a > b ? a : b; }
__device__ __forceinline__ void gload16(const void* g, void* l) {
    __builtin_amdgcn_global_load_lds(
        (const __attribute__((address_space(1))) unsigned int*)g,
        (__attribute__((address_space(3))) unsigned int*)l, 16, 0, 0);
}

// ---- init (8 blocks): exact e2[512]; embed^T hi/lo [code][hi64|lo64] bf16 PRE-SWIZZLED ----
__global__ __launch_bounds__(512) void vq_init(const float* __restrict__ eg, char* __restrict__ ws) {
    const int tid = threadIdx.x, blk = blockIdx.x;
    if (tid < 64) {
        int n = blk * 64 + tid;
        float s = 0.f;
        #pragma unroll 8
        for (int k = 0; k < CC; ++k) { float v = eg[k * NE + n]; s = __fadd_rn(s, __fmul_rn(v, v)); }
        ((float*)(ws + E2_OFF))[n] = s;
    }
    char* et = ws + ET_OFF;
    #pragma unroll
    for (int it = 0; it < 8; ++it) {
        int idx = blk * 4096 + it * 512 + tid;   // global word index
        int n = idx >> 6, w = idx & 63;
        int k = (w & 31) << 1;
        float v0 = eg[k * NE + n], v1 = eg[(k + 1) * NE + n];
        unsigned short c0, c1;
        if (w < 32) { c0 = f2bf(v0); c1 = f2bf(v1); }
        else {
            unsigned short h0 = f2bf(v0), h1 = f2bf(v1);
            c0 = f2bf(__fsub_rn(v0, bf2f(h0)));
            c1 = f2bf(__fsub_rn(v1, bf2f(h1)));
        }
        int b = (n * 256 + w * 4) ^ ((n & 15) << 4);   // row-local XOR swizzle (matches reader)
        *(unsigned int*)(et + b) = (unsigned int)c0 | ((unsigned int)c1 << 16);
    }
    unsigned int* h32 = (unsigned int*)(ws + HIST_OFF);
    for (int i = blk * 2048 + tid; i < (blk + 1) * 2048; i += 512) h32[i] = 0u;
    if (blk == 0 && tid < 32) ((float*)(ws + BATCH_OFF))[tid] = 0.f;
}

// ---- K1: split-bf16 screen (r14-proven math), XCD-coherent quarter mapping:
// q = blk>>10, tile = blk&1023 -> a tile's 4 quarters are blocks {t, t+1024, t+2048,
// t+3072}, all = t (mod 8) -> SAME XCD -> shared L2 for the x-tile and et-quarter. ----
__global__ __launch_bounds__(256) void vq_screen(const float* __restrict__ xg,
                                                 char* __restrict__ ws) {
    __shared__ __align__(16) char btb[32768];   // 128 codes x 256 B (hi|lo), swizzled
    __shared__ float e2q[128];

    const int tid  = threadIdx.x;
    const int lane = tid & 63;
    const int wv   = tid >> 6;
    const int l15  = lane & 15;
    const int l4   = lane >> 4;
    const int blk  = blockIdx.x;
    const int q    = blk >> 10;          // quarter (generation)
    const int tile = blk & 1023;         // pixel tile
    const int pix0 = tile * PIXB;
    const int bb   = pix0 >> 12;
    const size_t xbase = (size_t)bb * CHWSZ + (pix0 & 4095);

    #pragma unroll
    for (int i = 0; i < 8; ++i)
        gload16(ws + ET_OFF + (size_t)q * 32768 + i * 4096 + tid * 16, &btb[i * 4096 + tid * 16]);
    if (tid < 128) e2q[tid] = ((const float*)(ws + E2_OFF))[q * 128 + tid] + 512.f;   // biased

    bf16x8 ah[2][2], al[2][2];
    #pragma unroll
    for (int mt = 0; mt < 2; ++mt) {
        const int p = (2 * wv + mt) * 16 + l15;
        #pragma unroll
        for (int kh = 0; kh < 2; ++kh) {
            float v[8];
            #pragma unroll
            for (int e = 0; e < 8; ++e)
                v[e] = xg[xbase + (size_t)(kh * 32 + l4 * 8 + e) * HWSZ + p];
            bf16x8 hv, lv;
            #pragma unroll
            for (int e = 0; e < 8; ++e) {
                __bf16 hb = (__bf16)v[e];
                hv[e] = hb;
                lv[e] = (__bf16)__fsub_rn(v[e], (float)hb);
            }
            ah[mt][kh] = hv;
            al[mt][kh] = lv;
        }
    }
    asm volatile("s_waitcnt vmcnt(0) lgkmcnt(0)" ::: "memory");
    __builtin_amdgcn_sched_barrier(0);
    __builtin_amdgcn_s_barrier();          // the ONLY barrier: btb + e2q resident
    __builtin_amdgcn_sched_barrier(0);

    unsigned k1[2][4], k2[2][4];
    #pragma unroll
    for (int mt = 0; mt < 2; ++mt)
        #pragma unroll
        for (int r = 0; r < 4; ++r) { k1[mt][r] = 0xFFFFFFFFu; k2[mt][r] = 0xFFFFFFFFu; }

    #pragma unroll
    for (int gg = 0; gg < 8; ++gg) {
        const int r = gg * 16 + l15;          // quarter-local code 0..127
        const int ro = r * 256 + l4 * 16;
        const int sw2 = (r & 15) << 4;
        bf16x8 bh0 = *(const bf16x8*)(btb + ((ro +   0) ^ sw2));
        bf16x8 bh1 = *(const bf16x8*)(btb + ((ro +  64) ^ sw2));
        bf16x8 bl0 = *(const bf16x8*)(btb + ((ro + 128) ^ sw2));
        bf16x8 bl1 = *(const bf16x8*)(btb + ((ro + 192) ^ sw2));
        float e2v = e2q[r];
        #pragma unroll
        for (int mt = 0; mt < 2; ++mt) {
            f32x4 acc = (f32x4){0.f, 0.f, 0.f, 0.f};
            acc = __builtin_amdgcn_mfma_f32_16x16x32_bf16(ah[mt][0], bh0, acc, 0, 0, 0);
            acc = __builtin_amdgcn_mfma_f32_16x16x32_bf16(ah[mt][1], bh1, acc, 0, 0, 0);
            acc = __builtin_amdgcn_mfma_f32_16x16x32_bf16(ah[mt][0], bl0, acc, 0, 0, 0);
            acc = __builtin_amdgcn_mfma_f32_16x16x32_bf16(ah[mt][1], bl1, acc, 0, 0, 0);
            acc = __builtin_amdgcn_mfma_f32_16x16x32_bf16(al[mt][0], bh0, acc, 0, 0, 0);
            acc = __builtin_amdgcn_mfma_f32_16x16x32_bf16(al[mt][1], bh1, acc, 0, 0, 0);
            #pragma unroll
            for (int r2 = 0; r2 < 4; ++r2) {
                float d = __fmaf_rn(-2.f, acc[r2], e2v);       // biased +512, > 0
                unsigned u = (__builtin_bit_cast(unsigned, d) & 0xFFFFFF80u) | (unsigned)r;
                k2[mt][r2] = umin_(k2[mt][r2], umax_(u, k1[mt][r2]));
                k1[mt][r2] = umin_(k1[mt][r2], u);
            }
        }
    }

    #pragma unroll
    for (int m = 1; m < 16; m <<= 1) {
        #pragma unroll
        for (int mt = 0; mt < 2; ++mt)
            #pragma unroll
            for (int r = 0; r < 4; ++r) {
                unsigned o1 = __shfl_xor(k1[mt][r], m, 64);
                unsigned o2 = __shfl_xor(k2[mt][r], m, 64);
                k2[mt][r] = umin_(umin_(k2[mt][r], o2), umax_(k1[mt][r], o1));
                k1[mt][r] = umin_(k1[mt][r], o1);
            }
    }

    if (l15 == 0) {
        uint2* part = (uint2*)(ws + PART_OFF);
        #pragma unroll
        for (int mt = 0; mt < 2; ++mt)
            #pragma unroll
            for (int r = 0; r < 4; ++r) {
                int p = wv * 32 + mt * 16 + l4 * 4 + r;
                part[(size_t)(pix0 + p) * 4 + q] = (uint2){k1[mt][r], k2[mt][r]};
            }
    }
}

// ---- K2: fused combine + 8-candidate recheck (full-512 fallback) + hist + apply + sq ----
__global__ __launch_bounds__(256) void vq_apply(const float* __restrict__ xg,
                                                const float* __restrict__ eg,
                                                float* __restrict__ outg,
                                                char* __restrict__ ws) {
    __shared__ int idxs[PIXB];
    __shared__ unsigned char flg[PIXB];
    __shared__ float e2s[NE];
    __shared__ float xp[4][CC];
    __shared__ float wsum[4];

    const int tid  = threadIdx.x;
    const int lane = tid & 63;
    const int wv   = tid >> 6;
    const int pix0 = blockIdx.x * PIXB;
    const int bb   = pix0 >> 12;
    const size_t xbase = (size_t)bb * CHWSZ + (pix0 & 4095);

    {
        const float* e2g = (const float*)(ws + E2_OFF);
        for (int t = tid; t < NE; t += 256) e2s[t] = e2g[t];
    }

    // combine 4 quarters; classify: 0 = safe, 1 = candidate recheck, 2 = full fallback
    if (tid < PIXB) {
        const uint2* part = (const uint2*)(ws + PART_OFF) + (size_t)(pix0 + tid) * 4;
        uint2 pq[4];
        #pragma unroll
        for (int q = 0; q < 4; ++q) pq[q] = part[q];
        unsigned K1 = 0xFFFFFFFFu, K2 = 0xFFFFFFFFu;
        int gq = 0;
        #pragma unroll
        for (int q = 0; q < 4; ++q) {
            K2 = umin_(umin_(K2, pq[q].y), umax_(K1, pq[q].x));
            if (pq[q].x < K1) { K1 = pq[q].x; gq = q; }
        }
        float M1 = bcf(K1 & 0xFFFFFF80u);
        float M2 = bcf(K2 & 0xFFFFFF80u);
        int fb = 0;
        #pragma unroll
        for (int q = 0; q < 4; ++q) {
            float m1q = bcf(pq[q].x & 0xFFFFFF80u);
            float m2q = bcf(pq[q].y & 0xFFFFFF80u);
            if (m1q - M1 < FB_T && m2q - m1q < FB_T) fb = 1;   // 3-code cluster risk
        }
        idxs[tid] = gq * 128 + (int)(K1 & 127u);
        flg[tid] = (M2 - M1 < FLAG_T) ? (fb ? 2 : 1) : 0;
    }
    __syncthreads();

    // per-wave recheck over its 32 pixels
    {
        bool f = (lane < 32) ? (flg[wv * 32 + lane] != 0) : false;
        unsigned long long mask = __ballot(f);
        while (mask) {
            int l0 = __ffsll((long long)mask) - 1;
            mask &= mask - 1;
            int p = wv * 32 + l0;
            int mode = flg[p];
            xp[wv][lane] = xg[xbase + (size_t)lane * HWSZ + p];   // k = lane
            float rr[8];
            #pragma unroll
            for (int u = 0; u < 8; ++u) { float v = xp[wv][u]; rr[u] = __fmul_rn(v, v); }
            #pragma unroll
            for (int t2 = 1; t2 < 8; ++t2)
                #pragma unroll
                for (int u = 0; u < 8; ++u) { float v = xp[wv][t2 * 8 + u]; rr[u] = __fadd_rn(rr[u], __fmul_rn(v, v)); }
            float f2 = __fadd_rn(__fadd_rn(__fadd_rn(rr[0], rr[1]), __fadd_rn(rr[2], rr[3])),
                                 __fadd_rn(__fadd_rn(rr[4], rr[5]), __fadd_rn(rr[6], rr[7])));
            if (mode == 1) {
                // 8 candidates: quarter {min1, min2}; lane j<8 evaluates candidate j with
                // the bit-identical sequential-k fp32 chain.
                float d = 3.4e38f; int c = 0x7FFFFFFF;
                if (lane < 8) {
                    const uint2* part = (const uint2*)(ws + PART_OFF) + (size_t)(pix0 + p) * 4;
                    uint2 pq = part[lane >> 1];
                    unsigned key = (lane & 1) ? pq.y : pq.x;
                    c = (lane >> 1) * 128 + (int)(key & 127u);
                    float dot = 0.f;
                    #pragma unroll 8
                    for (int k = 0; k < CC; ++k) dot = __fmaf_rn(xp[wv][k], eg[k * NE + c], dot);
                    d = __fadd_rn(__fmaf_rn(-2.f, dot, f2), e2s[c]);
                }
                #pragma unroll
                for (int m = 1; m < 8; m <<= 1) {
                    float ov = __shfl_xor(d, m, 64);
                    int   oi = __shfl_xor(c, m, 64);
                    if (ov < d || (ov == d && oi < c)) { d = ov; c = oi; }
                }
                int nb = __shfl(c, 0, 64);
                if (lane == 0) idxs[p] = nb;
            } else {
                // full 512-code fallback (rare) — bit-identical fp32 arithmetic
                const int c0 = lane * 8;
                float dot[8];
                #pragma unroll
                for (int j = 0; j < 8; ++j) dot[j] = 0.f;
                #pragma unroll 4
                for (int k = 0; k < CC; ++k) {
                    float xv = xp[wv][k];
                    float4 aa = *(const float4*)(eg + k * NE + c0);
                    float4 bbv = *(const float4*)(eg + k * NE + c0 + 4);
                    dot[0] = __fmaf_rn(xv, aa.x, dot[0]); dot[1] = __fmaf_rn(xv, aa.y, dot[1]);
                    dot[2] = __fmaf_rn(xv, aa.z, dot[2]); dot[3] = __fmaf_rn(xv, aa.w, dot[3]);
                    dot[4] = __fmaf_rn(xv, bbv.x, dot[4]); dot[5] = __fmaf_rn(xv, bbv.y, dot[5]);
                    dot[6] = __fmaf_rn(xv, bbv.z, dot[6]); dot[7] = __fmaf_rn(xv, bbv.w, dot[7]);
                }
                float best = 3.4e38f; int bidx = 0;
                #pragma unroll
                for (int j = 0; j < 8; ++j) {
                    float d = __fadd_rn(__fmaf_rn(-2.f, dot[j], f2), e2s[c0 + j]);
                    if (d < best) { best = d; bidx = c0 + j; }
                }
                #pragma unroll
                for (int m = 1; m < 64; m <<= 1) {
                    float ov = __shfl_xor(best, m, 64);
                    int   oi = __shfl_xor(bidx, m, 64);
                    if (ov < best || (ov == best && oi < bidx)) { best = ov; bidx = oi; }
                }
                if (lane == 0) idxs[p] = bidx;
            }
        }
    }
    __syncthreads();

    if (tid < PIXB)
        atomicAdd((unsigned int*)(ws + HIST_OFF) + (blockIdx.x & (NSTRIPE - 1)) * NE + idxs[tid], 1u);

    // apply: float4 x re-read; exact ref arithmetic out = x + (q - x); sq loss
    float sq = 0.f;
    for (int t = tid; t < 2048; t += 256) {
        int cc = t >> 5, p4 = (t & 31) << 2;
        float4 vr = *(const float4*)(xg + xbase + (size_t)cc * HWSZ + p4);
        float vv[4] = {vr.x, vr.y, vr.z, vr.w};
        float4 ov;
        float* ovp = &ov.x;
        #pragma unroll
        for (int j = 0; j < 4; ++j) {
            float qv = eg[cc * NE + idxs[p4 + j]];
            float d = __fsub_rn(qv, vv[j]);
            ovp[j] = __fadd_rn(vv[j], d);
            sq = __fmaf_rn(d, d, sq);
        }
        *(float4*)(outg + xbase + (size_t)cc * HWSZ + p4) = ov;
    }
    #pragma unroll
    for (int m = 32; m >= 1; m >>= 1) sq += __shfl_down(sq, m, 64);
    if (lane == 0) wsum[wv] = sq;
    __syncthreads();
    if (tid == 0) atomicAdd((float*)(ws + BATCH_OFF) + bb, wsum[0] + wsum[1] + wsum[2] + wsum[3]);
}

// ---- finalize: sum hist stripes, diff[32], perplexity ----
__global__ __launch_bounds__(512) void vq_fin(const char* __restrict__ ws, float* __restrict__ outg) {
    __shared__ float acc8[8];
    const int tid = threadIdx.x, lane = tid & 63, wv = tid >> 6;
    const unsigned int* h32 = (const unsigned int*)(ws + HIST_OFF);
    unsigned int h = 0;
    #pragma unroll
    for (int s = 0; s < NSTRIPE; ++s) h += h32[s * NE + tid];
    float p = (float)h * (1.f / (float)NPIX);
    float t = p * logf(p + 1e-10f);
    #pragma unroll
    for (int m = 32; m >= 1; m >>= 1) t += __shfl_down(t, m, 64);
    if (lane == 0) acc8[wv] = t;
    __syncthreads();
    if (tid < 32) outg[8388608 + tid] = ((const float*)(ws + BATCH_OFF))[tid] * (1.f / 262144.f);
    if (tid == 0) {
        float s = 0.f;
        #pragma unroll
        for (int u = 0; u < 8; ++u) s += acc8[u];
        outg[8388640] = expf(-s);
    }
}

extern "C" void kernel_launch(void* const* d_in, const int* in_sizes, int n_in,
                              void* d_out, int out_size, void* d_ws, size_t ws_size,
                              hipStream_t stream) {
    const float* xg = (const float*)d_in[0];
    const float* eg = (const float*)d_in[1];
    float* outg = (float*)d_out;
    char* ws = (char*)d_ws;
    vq_init<<<8, 512, 0, stream>>>(eg, ws);
    vq_screen<<<(NPIX / PIXB) * 4, 256, 0, stream>>>(xg, ws);
    vq_apply<<<NPIX / PIXB, 256, 0, stream>>>(xg, eg, outg, ws);
    vq_fin<<<1, 512, 0, stream>>>(ws, outg);
}

// Round 23
// 69.013 us; speedup vs baseline: 2.9713x; 1.0204x over previous
//
#include <hip/hip_runtime.h>

typedef __bf16 bf16x8 __attribute__((ext_vector_type(8)));
typedef float  f32x4  __attribute__((ext_vector_type(4)));

#define CC 64
#define HWSZ 4096
#define CHWSZ 262144
#define NE 512
#define NPIX 131072
#define PIXB 128
#define FLAG_T 0.024f         // 0.012 split-err + mask quantum + slack (r16-proven)
#define FB_T   0.05f          // 3-code-cluster fallback threshold
#define NSTRIPE 32

#define ET_OFF 0              // 512 codes * 256 B (hi64|lo64 bf16), XOR-swizzled rows
#define E2_OFF 131072         // 512 * 4
#define HIST_OFF 133120       // 32 stripes * 512 * 4 = 65536
#define BATCH_OFF 198656      // 32 * 4
#define PART_OFF 198784       // 131072 pixels * 4 quarters * 8 B = 4194304

__device__ __forceinline__ float bf2f(unsigned short u) {
    unsigned int x = ((unsigned int)u) << 16;
    return __builtin_bit_cast(float, x);
}
__device__ __forceinline__ unsigned short f2bf(float f) {
    unsigned int x = __builtin_bit_cast(unsigned int, f);
    unsigned int r = x + 0x7fffu + ((x >> 16) & 1u);
    return (unsigned short)(r >> 16);
}
__device__ __forceinline__ float bcf(unsigned u) { return __builtin_bit_cast(float, u); }
__device__ __forceinline__ unsigned umin_(unsigned a, unsigned b) { return a < b ? a : b; }
__device__ __forceinline__ unsigned umax_(unsigned a, unsigned b) { return a > b ? a : b; }
__device__ __forceinline__ void gload16(const void* g, void* l) {
    __builtin_amdgcn_global_load_lds(
        (const __attribute__((address_space(1))) unsigned int*)g,
        (__attribute__((address_space(3))) unsigned int*)l, 16, 0, 0);
}

// ---- init (64 blocks x 256 thr — widened from 8x512; same per-code arithmetic):
// exact e2[512] (sequential-k, bit-identical); embed^T hi/lo bf16 PRE-SWIZZLED ----
__global__ __launch_bounds__(256) void vq_init(const float* __restrict__ eg, char* __restrict__ ws) {
    const int tid = threadIdx.x, blk = blockIdx.x;
    if (tid < 8) {
        int n = blk * 8 + tid;
        float s = 0.f;
        #pragma unroll 8
        for (int k = 0; k < CC; ++k) { float v = eg[k * NE + n]; s = __fadd_rn(s, __fmul_rn(v, v)); }
        ((float*)(ws + E2_OFF))[n] = s;
    }
    char* et = ws + ET_OFF;
    #pragma unroll
    for (int it = 0; it < 2; ++it) {
        int idx = blk * 512 + it * 256 + tid;    // global word index (same space as before)
        int n = idx >> 6, w = idx & 63;
        int k = (w & 31) << 1;
        float v0 = eg[k * NE + n], v1 = eg[(k + 1) * NE + n];
        unsigned short c0, c1;
        if (w < 32) { c0 = f2bf(v0); c1 = f2bf(v1); }
        else {
            unsigned short h0 = f2bf(v0), h1 = f2bf(v1);
            c0 = f2bf(__fsub_rn(v0, bf2f(h0)));
            c1 = f2bf(__fsub_rn(v1, bf2f(h1)));
        }
        int b = (n * 256 + w * 4) ^ ((n & 15) << 4);   // row-local XOR swizzle (matches reader)
        *(unsigned int*)(et + b) = (unsigned int)c0 | ((unsigned int)c1 << 16);
    }
    ((unsigned int*)(ws + HIST_OFF))[blk * 256 + tid] = 0u;   // 64*256 = 16384 words
    if (blk == 0 && tid < 32) ((float*)(ws + BATCH_OFF))[tid] = 0.f;
}

// ---- K1: split-bf16 screen (r16-verified, byte-identical): A direct global->reg,
// B quarter in LDS, packed-key (7-bit code) argmin, XCD-coherent quarter mapping. ----
__global__ __launch_bounds__(256) void vq_screen(const float* __restrict__ xg,
                                                 char* __restrict__ ws) {
    __shared__ __align__(16) char btb[32768];   // 128 codes x 256 B (hi|lo), swizzled
    __shared__ float e2q[128];

    const int tid  = threadIdx.x;
    const int lane = tid & 63;
    const int wv   = tid >> 6;
    const int l15  = lane & 15;
    const int l4   = lane >> 4;
    const int blk  = blockIdx.x;
    const int q    = blk >> 10;          // quarter (generation)
    const int tile = blk & 1023;         // pixel tile
    const int pix0 = tile * PIXB;
    const int bb   = pix0 >> 12;
    const size_t xbase = (size_t)bb * CHWSZ + (pix0 & 4095);

    #pragma unroll
    for (int i = 0; i < 8; ++i)
        gload16(ws + ET_OFF + (size_t)q * 32768 + i * 4096 + tid * 16, &btb[i * 4096 + tid * 16]);
    if (tid < 128) e2q[tid] = ((const float*)(ws + E2_OFF))[q * 128 + tid] + 512.f;   // biased

    bf16x8 ah[2][2], al[2][2];
    #pragma unroll
    for (int mt = 0; mt < 2; ++mt) {
        const int p = (2 * wv + mt) * 16 + l15;
        #pragma unroll
        for (int kh = 0; kh < 2; ++kh) {
            float v[8];
            #pragma unroll
            for (int e = 0; e < 8; ++e)
                v[e] = xg[xbase + (size_t)(kh * 32 + l4 * 8 + e) * HWSZ + p];
            bf16x8 hv, lv;
            #pragma unroll
            for (int e = 0; e < 8; ++e) {
                __bf16 hb = (__bf16)v[e];
                hv[e] = hb;
                lv[e] = (__bf16)__fsub_rn(v[e], (float)hb);
            }
            ah[mt][kh] = hv;
            al[mt][kh] = lv;
        }
    }
    asm volatile("s_waitcnt vmcnt(0) lgkmcnt(0)" ::: "memory");
    __builtin_amdgcn_sched_barrier(0);
    __builtin_amdgcn_s_barrier();          // the ONLY barrier: btb + e2q resident
    __builtin_amdgcn_sched_barrier(0);

    unsigned k1[2][4], k2[2][4];
    #pragma unroll
    for (int mt = 0; mt < 2; ++mt)
        #pragma unroll
        for (int r = 0; r < 4; ++r) { k1[mt][r] = 0xFFFFFFFFu; k2[mt][r] = 0xFFFFFFFFu; }

    #pragma unroll
    for (int gg = 0; gg < 8; ++gg) {
        const int r = gg * 16 + l15;          // quarter-local code 0..127
        const int ro = r * 256 + l4 * 16;
        const int sw2 = (r & 15) << 4;
        bf16x8 bh0 = *(const bf16x8*)(btb + ((ro +   0) ^ sw2));
        bf16x8 bh1 = *(const bf16x8*)(btb + ((ro +  64) ^ sw2));
        bf16x8 bl0 = *(const bf16x8*)(btb + ((ro + 128) ^ sw2));
        bf16x8 bl1 = *(const bf16x8*)(btb + ((ro + 192) ^ sw2));
        float e2v = e2q[r];
        #pragma unroll
        for (int mt = 0; mt < 2; ++mt) {
            f32x4 acc = (f32x4){0.f, 0.f, 0.f, 0.f};
            acc = __builtin_amdgcn_mfma_f32_16x16x32_bf16(ah[mt][0], bh0, acc, 0, 0, 0);
            acc = __builtin_amdgcn_mfma_f32_16x16x32_bf16(ah[mt][1], bh1, acc, 0, 0, 0);
            acc = __builtin_amdgcn_mfma_f32_16x16x32_bf16(ah[mt][0], bl0, acc, 0, 0, 0);
            acc = __builtin_amdgcn_mfma_f32_16x16x32_bf16(ah[mt][1], bl1, acc, 0, 0, 0);
            acc = __builtin_amdgcn_mfma_f32_16x16x32_bf16(al[mt][0], bh0, acc, 0, 0, 0);
            acc = __builtin_amdgcn_mfma_f32_16x16x32_bf16(al[mt][1], bh1, acc, 0, 0, 0);
            #pragma unroll
            for (int r2 = 0; r2 < 4; ++r2) {
                float d = __fmaf_rn(-2.f, acc[r2], e2v);       // biased +512, > 0
                unsigned u = (__builtin_bit_cast(unsigned, d) & 0xFFFFFF80u) | (unsigned)r;
                k2[mt][r2] = umin_(k2[mt][r2], umax_(u, k1[mt][r2]));
                k1[mt][r2] = umin_(k1[mt][r2], u);
            }
        }
    }

    #pragma unroll
    for (int m = 1; m < 16; m <<= 1) {
        #pragma unroll
        for (int mt = 0; mt < 2; ++mt)
            #pragma unroll
            for (int r = 0; r < 4; ++r) {
                unsigned o1 = __shfl_xor(k1[mt][r], m, 64);
                unsigned o2 = __shfl_xor(k2[mt][r], m, 64);
                k2[mt][r] = umin_(umin_(k2[mt][r], o2), umax_(k1[mt][r], o1));
                k1[mt][r] = umin_(k1[mt][r], o1);
            }
    }

    if (l15 == 0) {
        uint2* part = (uint2*)(ws + PART_OFF);
        #pragma unroll
        for (int mt = 0; mt < 2; ++mt)
            #pragma unroll
            for (int r = 0; r < 4; ++r) {
                int p = wv * 32 + mt * 16 + l4 * 4 + r;
                part[(size_t)(pix0 + p) * 4 + q] = (uint2){k1[mt][r], k2[mt][r]};
            }
    }
}

// ---- K2: fused combine + 8-candidate recheck (full-512 fallback) + hist + apply + sq ----
__global__ __launch_bounds__(256) void vq_apply(const float* __restrict__ xg,
                                                const float* __restrict__ eg,
                                                float* __restrict__ outg,
                                                char* __restrict__ ws) {
    __shared__ int idxs[PIXB];
    __shared__ unsigned char flg[PIXB];
    __shared__ float e2s[NE];
    __shared__ float xp[4][CC];
    __shared__ float wsum[4];

    const int tid  = threadIdx.x;
    const int lane = tid & 63;
    const int wv   = tid >> 6;
    const int pix0 = blockIdx.x * PIXB;
    const int bb   = pix0 >> 12;
    const size_t xbase = (size_t)bb * CHWSZ + (pix0 & 4095);

    {
        const float* e2g = (const float*)(ws + E2_OFF);
        for (int t = tid; t < NE; t += 256) e2s[t] = e2g[t];
    }

    // combine 4 quarters; classify: 0 = safe, 1 = candidate recheck, 2 = full fallback
    if (tid < PIXB) {
        const uint2* part = (const uint2*)(ws + PART_OFF) + (size_t)(pix0 + tid) * 4;
        uint2 pq[4];
        #pragma unroll
        for (int q = 0; q < 4; ++q) pq[q] = part[q];
        unsigned K1 = 0xFFFFFFFFu, K2 = 0xFFFFFFFFu;
        int gq = 0;
        #pragma unroll
        for (int q = 0; q < 4; ++q) {
            K2 = umin_(umin_(K2, pq[q].y), umax_(K1, pq[q].x));
            if (pq[q].x < K1) { K1 = pq[q].x; gq = q; }
        }
        float M1 = bcf(K1 & 0xFFFFFF80u);
        float M2 = bcf(K2 & 0xFFFFFF80u);
        int fb = 0;
        #pragma unroll
        for (int q = 0; q < 4; ++q) {
            float m1q = bcf(pq[q].x & 0xFFFFFF80u);
            float m2q = bcf(pq[q].y & 0xFFFFFF80u);
            if (m1q - M1 < FB_T && m2q - m1q < FB_T) fb = 1;   // 3-code cluster risk
        }
        idxs[tid] = gq * 128 + (int)(K1 & 127u);
        flg[tid] = (M2 - M1 < FLAG_T) ? (fb ? 2 : 1) : 0;
    }
    __syncthreads();

    // per-wave recheck over its 32 pixels
    {
        bool f = (lane < 32) ? (flg[wv * 32 + lane] != 0) : false;
        unsigned long long mask = __ballot(f);
        while (mask) {
            int l0 = __ffsll((long long)mask) - 1;
            mask &= mask - 1;
            int p = wv * 32 + l0;
            int mode = flg[p];
            xp[wv][lane] = xg[xbase + (size_t)lane * HWSZ + p];   // k = lane
            float rr[8];
            #pragma unroll
            for (int u = 0; u < 8; ++u) { float v = xp[wv][u]; rr[u] = __fmul_rn(v, v); }
            #pragma unroll
            for (int t2 = 1; t2 < 8; ++t2)
                #pragma unroll
                for (int u = 0; u < 8; ++u) { float v = xp[wv][t2 * 8 + u]; rr[u] = __fadd_rn(rr[u], __fmul_rn(v, v)); }
            float f2 = __fadd_rn(__fadd_rn(__fadd_rn(rr[0], rr[1]), __fadd_rn(rr[2], rr[3])),
                                 __fadd_rn(__fadd_rn(rr[4], rr[5]), __fadd_rn(rr[6], rr[7])));
            if (mode == 1) {
                // 8 candidates: quarter {min1, min2}; lane j<8 evaluates candidate j with
                // the bit-identical sequential-k fp32 chain.
                float d = 3.4e38f; int c = 0x7FFFFFFF;
                if (lane < 8) {
                    const uint2* part = (const uint2*)(ws + PART_OFF) + (size_t)(pix0 + p) * 4;
                    uint2 pq = part[lane >> 1];
                    unsigned key = (lane & 1) ? pq.y : pq.x;
                    c = (lane >> 1) * 128 + (int)(key & 127u);
                    float dot = 0.f;
                    #pragma unroll 8
                    for (int k = 0; k < CC; ++k) dot = __fmaf_rn(xp[wv][k], eg[k * NE + c], dot);
                    d = __fadd_rn(__fmaf_rn(-2.f, dot, f2), e2s[c]);
                }
                #pragma unroll
                for (int m = 1; m < 8; m <<= 1) {
                    float ov = __shfl_xor(d, m, 64);
                    int   oi = __shfl_xor(c, m, 64);
                    if (ov < d || (ov == d && oi < c)) { d = ov; c = oi; }
                }
                int nb = __shfl(c, 0, 64);
                if (lane == 0) idxs[p] = nb;
            } else {
                // full 512-code fallback (rare) — bit-identical fp32 arithmetic
                const int c0 = lane * 8;
                float dot[8];
                #pragma unroll
                for (int j = 0; j < 8; ++j) dot[j] = 0.f;
                #pragma unroll 4
                for (int k = 0; k < CC; ++k) {
                    float xv = xp[wv][k];
                    float4 aa = *(const float4*)(eg + k * NE + c0);
                    float4 bbv = *(const float4*)(eg + k * NE + c0 + 4);
                    dot[0] = __fmaf_rn(xv, aa.x, dot[0]); dot[1] = __fmaf_rn(xv, aa.y, dot[1]);
                    dot[2] = __fmaf_rn(xv, aa.z, dot[2]); dot[3] = __fmaf_rn(xv, aa.w, dot[3]);
                    dot[4] = __fmaf_rn(xv, bbv.x, dot[4]); dot[5] = __fmaf_rn(xv, bbv.y, dot[5]);
                    dot[6] = __fmaf_rn(xv, bbv.z, dot[6]); dot[7] = __fmaf_rn(xv, bbv.w, dot[7]);
                }
                float best = 3.4e38f; int bidx = 0;
                #pragma unroll
                for (int j = 0; j < 8; ++j) {
                    float d = __fadd_rn(__fmaf_rn(-2.f, dot[j], f2), e2s[c0 + j]);
                    if (d < best) { best = d; bidx = c0 + j; }
                }
                #pragma unroll
                for (int m = 1; m < 64; m <<= 1) {
                    float ov = __shfl_xor(best, m, 64);
                    int   oi = __shfl_xor(bidx, m, 64);
                    if (ov < best || (ov == best && oi < bidx)) { best = ov; bidx = oi; }
                }
                if (lane == 0) idxs[p] = bidx;
            }
        }
    }
    __syncthreads();

    if (tid < PIXB)
        atomicAdd((unsigned int*)(ws + HIST_OFF) + (blockIdx.x & (NSTRIPE - 1)) * NE + idxs[tid], 1u);

    // apply: float4 x re-read; exact ref arithmetic out = x + (q - x); sq loss
    float sq = 0.f;
    for (int t = tid; t < 2048; t += 256) {
        int cc = t >> 5, p4 = (t & 31) << 2;
        float4 vr = *(const float4*)(xg + xbase + (size_t)cc * HWSZ + p4);
        float vv[4] = {vr.x, vr.y, vr.z, vr.w};
        float4 ov;
        float* ovp = &ov.x;
        #pragma unroll
        for (int j = 0; j < 4; ++j) {
            float qv = eg[cc * NE + idxs[p4 + j]];
            float d = __fsub_rn(qv, vv[j]);
            ovp[j] = __fadd_rn(vv[j], d);
            sq = __fmaf_rn(d, d, sq);
        }
        *(float4*)(outg + xbase + (size_t)cc * HWSZ + p4) = ov;
    }
    #pragma unroll
    for (int m = 32; m >= 1; m >>= 1) sq += __shfl_down(sq, m, 64);
    if (lane == 0) wsum[wv] = sq;
    __syncthreads();
    if (tid == 0) atomicAdd((float*)(ws + BATCH_OFF) + bb, wsum[0] + wsum[1] + wsum[2] + wsum[3]);
}

// ---- finalize: sum hist stripes, diff[32], perplexity ----
__global__ __launch_bounds__(512) void vq_fin(const char* __restrict__ ws, float* __restrict__ outg) {
    __shared__ float acc8[8];
    const int tid = threadIdx.x, lane = tid & 63, wv = tid >> 6;
    const unsigned int* h32 = (const unsigned int*)(ws + HIST_OFF);
    unsigned int h = 0;
    #pragma unroll
    for (int s = 0; s < NSTRIPE; ++s) h += h32[s * NE + tid];
    float p = (float)h * (1.f / (float)NPIX);
    float t = p * logf(p + 1e-10f);
    #pragma unroll
    for (int m = 32; m >= 1; m >>= 1) t += __shfl_down(t, m, 64);
    if (lane == 0) acc8[wv] = t;
    __syncthreads();
    if (tid < 32) outg[8388608 + tid] = ((const float*)(ws + BATCH_OFF))[tid] * (1.f / 262144.f);
    if (tid == 0) {
        float s = 0.f;
        #pragma unroll
        for (int u = 0; u < 8; ++u) s += acc8[u];
        outg[8388640] = expf(-s);
    }
}

extern "C" void kernel_launch(void* const* d_in, const int* in_sizes, int n_in,
                              void* d_out, int out_size, void* d_ws, size_t ws_size,
                              hipStream_t stream) {
    const float* xg = (const float*)d_in[0];
    const float* eg = (const float*)d_in[1];
    float* outg = (float*)d_out;
    char* ws = (char*)d_ws;
    vq_init<<<64, 256, 0, stream>>>(eg, ws);
    vq_screen<<<(NPIX / PIXB) * 4, 256, 0, stream>>>(xg, ws);
    vq_apply<<<NPIX / PIXB, 256, 0, stream>>>(xg, eg, outg, ws);
    vq_fin<<<1, 512, 0, stream>>>(ws, outg);
}